// Round 13
// baseline (1239.342 us; speedup 1.0000x reference)
//
#include <hip/hip_runtime.h>

typedef __bf16 bf16_t;
typedef __bf16 bf16x8 __attribute__((ext_vector_type(8)));
typedef float  f32x4  __attribute__((ext_vector_type(4)));

#define BSZ 64
#define NNODE 44
#define NODES (BSZ*NNODE)      /* 2816 */

__device__ __forceinline__ float  bf2f(bf16_t v){ return (float)v; }
__device__ __forceinline__ bf16_t f2bf(float v){ return (bf16_t)v; }
__device__ __forceinline__ float  silu_f(float v){ return v / (1.0f + __expf(-v)); }

// ---------------- batched transpose + f32->bf16: src (G,R,256) -> dst (G,256,ldo)
__global__ void transpose_wb(const float* __restrict__ src, bf16_t* __restrict__ dst,
                             int R, int ldo) {
  __shared__ bf16_t tile[32][33];
  int g = blockIdx.z;
  src += (size_t)g * R * 256;
  dst += (size_t)g * 256 * ldo;
  int n0 = blockIdx.x * 32, r0 = blockIdx.y * 32;
  int tx = threadIdx.x, ty = threadIdx.y;   // 32 x 8
  for (int p = 0; p < 32; p += 8) {
    int r = r0 + ty + p;
    if (r < R) tile[ty + p][tx] = f2bf(src[(size_t)r * 256 + n0 + tx]);
  }
  __syncthreads();
  for (int p = 0; p < 32; p += 8) {
    int r = r0 + tx;
    if (r < R) dst[(size_t)(n0 + ty + p) * ldo + r] = tile[tx][ty + p];
  }
}

// ---------------- rproj[b][c] = rep[b]@W_rep[:,c] + b_rep[c]
__global__ __launch_bounds__(256)
void repproj_kernel(const float* __restrict__ rep, const float* __restrict__ W_rep,
                    const float* __restrict__ b_rep, float* __restrict__ out) {
  int b = blockIdx.x, c = threadIdx.x;
  float acc = b_rep[c];
  const float* r = rep + (size_t)b * 512;
  for (int k = 0; k < 512; k++) acc += r[k] * W_rep[(size_t)k * 256 + c];
  out[(size_t)b * 256 + c] = acc;
}

// ---------------- embedding; writes h_f32, cat1[:, :256], x0, xA
__global__ __launch_bounds__(256)
void embed_kernel(const float* __restrict__ xh, const float* __restrict__ t,
                  const float* __restrict__ nmask,
                  const float* __restrict__ W_embed, const float* __restrict__ b_embed,
                  const float* __restrict__ repproj,
                  float* __restrict__ h_f32, bf16_t* __restrict__ cat1,
                  float* __restrict__ x0, float* __restrict__ x) {
  int m = blockIdx.x;
  int b = m / NNODE;
  int c = threadIdx.x;
  float nm = nmask[m];
  float acc = b_embed[c] + repproj[(size_t)b * 256 + c];
  for (int kk = 0; kk < 6; kk++)
    acc += xh[(size_t)m * 9 + 3 + kk] * nm * W_embed[(size_t)kk * 256 + c];
  acc += t[b] * W_embed[6 * 256 + c];
  h_f32[(size_t)m * 256 + c] = acc;
  cat1 [(size_t)m * 512 + c] = f2bf(acc);
  if (c < 3) {
    float xv = xh[(size_t)m * 9 + c] * nm;
    x0[(size_t)m * 3 + c] = xv;
    x [(size_t)m * 3 + c] = xv;
  }
}

// ---------------- PQ GEMM, BM=64 BN=64, 4 waves of 32x32, zero LDS.
__global__ __launch_bounds__(256)
void gemm_pq(const bf16_t* __restrict__ A, int lda,
             const bf16_t* __restrict__ BT, int ldbt,
             float* __restrict__ outPQ) {
  int tid = threadIdx.x;
  int m0 = blockIdx.y * 64, n0 = blockIdx.x * 64;
  int kof = (int)blockIdx.z * 256;
  int w = tid >> 6, lane = tid & 63, q = lane >> 4, lr = lane & 15;
  int wm = w & 1, wn = w >> 1;
  f32x4 acc[2][2];
  for (int a = 0; a < 2; a++) for (int bb = 0; bb < 2; bb++)
    for (int rr = 0; rr < 4; rr++) acc[a][bb][rr] = 0.0f;
  const bf16_t* Arow0 = A  + (size_t)(m0 + wm * 32 + lr) * lda;
  const bf16_t* Brow0 = BT + (size_t)(n0 + wn * 32 + lr) * ldbt + kof;
  for (int k0 = 0; k0 < 256; k0 += 32) {
    bf16x8 af[2], bfr[2];
    for (int mt = 0; mt < 2; mt++)
      af[mt]  = *(const bf16x8*)(Arow0 + (size_t)mt * 16 * lda + k0 + q * 8);
    for (int nt = 0; nt < 2; nt++)
      bfr[nt] = *(const bf16x8*)(Brow0 + (size_t)nt * 16 * ldbt + k0 + q * 8);
    for (int mt = 0; mt < 2; mt++)
      for (int nt = 0; nt < 2; nt++)
        acc[mt][nt] = __builtin_amdgcn_mfma_f32_16x16x32_bf16(af[mt], bfr[nt], acc[mt][nt], 0, 0, 0);
  }
  for (int mt = 0; mt < 2; mt++)
    for (int nt = 0; nt < 2; nt++) {
      int col = n0 + wn * 32 + nt * 16 + lr;
      for (int rr = 0; rr < 4; rr++) {
        int row = m0 + wm * 32 + mt * 16 + q * 4 + rr;
        outPQ[(size_t)row * 512 + (size_t)blockIdx.z * 256 + col] = acc[mt][nt][rr];
      }
    }
}

// ---------------- fused node MLP: h = (h + silu([h,agg]@Wn1+bn1)@Wn2 + bn2)*nm
// One block per 64 rows; GEMM1 (K=512) -> t1 in LDS -> GEMM2 (K=256) -> update.
__global__ __launch_bounds__(256)
void node_mlp(const bf16_t* __restrict__ cat1,
              const bf16_t* __restrict__ Wn1T,   // [256 n][512 k] slice
              const float* __restrict__ bn1, size_t ob1,
              const bf16_t* __restrict__ Wn2T,   // [256 n][256 k] slice
              const float* __restrict__ bn2, size_t ob2,
              const float* __restrict__ nmask,
              float* __restrict__ h, bf16_t* __restrict__ catb) {
  __shared__ __align__(16) bf16_t t1s[64][264];
  int tid = threadIdx.x;
  int m0 = blockIdx.x * 64;
  int w = tid >> 6, lane = tid & 63, q = lane >> 4, lr = lane & 15;
  f32x4 acc[4][4];
  for (int mt = 0; mt < 4; mt++) for (int nt = 0; nt < 4; nt++)
    for (int rr = 0; rr < 4; rr++) acc[mt][nt][rr] = 0.0f;
  const bf16_t* Arow = cat1 + (size_t)(m0 + lr) * 512;
  const bf16_t* Brow = Wn1T + (size_t)(w * 64 + lr) * 512;
  for (int k0 = 0; k0 < 512; k0 += 32) {
    bf16x8 af[4], bfr[4];
    for (int mt = 0; mt < 4; mt++)
      af[mt]  = *(const bf16x8*)(Arow + (size_t)mt * 16 * 512 + k0 + q * 8);
    for (int nt = 0; nt < 4; nt++)
      bfr[nt] = *(const bf16x8*)(Brow + (size_t)nt * 16 * 512 + k0 + q * 8);
    for (int mt = 0; mt < 4; mt++)
      for (int nt = 0; nt < 4; nt++)
        acc[mt][nt] = __builtin_amdgcn_mfma_f32_16x16x32_bf16(af[mt], bfr[nt], acc[mt][nt], 0, 0, 0);
  }
  for (int mt = 0; mt < 4; mt++)
    for (int nt = 0; nt < 4; nt++) {
      int col = w * 64 + nt * 16 + lr;
      float bc = bn1[ob1 + col];
      for (int rr = 0; rr < 4; rr++) {
        int row = mt * 16 + q * 4 + rr;
        t1s[row][col] = f2bf(silu_f(acc[mt][nt][rr] + bc));
      }
    }
  __syncthreads();
  f32x4 acc2[4][4];
  for (int mt = 0; mt < 4; mt++) for (int nt = 0; nt < 4; nt++)
    for (int rr = 0; rr < 4; rr++) acc2[mt][nt][rr] = 0.0f;
  const bf16_t* Brow2 = Wn2T + (size_t)(w * 64 + lr) * 256;
  for (int k0 = 0; k0 < 256; k0 += 32) {
    bf16x8 af[4], bfr[4];
    for (int mt = 0; mt < 4; mt++)
      af[mt]  = *(const bf16x8*)(&t1s[mt * 16 + lr][k0 + q * 8]);
    for (int nt = 0; nt < 4; nt++)
      bfr[nt] = *(const bf16x8*)(Brow2 + (size_t)nt * 16 * 256 + k0 + q * 8);
    for (int mt = 0; mt < 4; mt++)
      for (int nt = 0; nt < 4; nt++)
        acc2[mt][nt] = __builtin_amdgcn_mfma_f32_16x16x32_bf16(af[mt], bfr[nt], acc2[mt][nt], 0, 0, 0);
  }
  for (int mt = 0; mt < 4; mt++)
    for (int nt = 0; nt < 4; nt++) {
      int col = w * 64 + nt * 16 + lr;
      float bc = bn2[ob2 + col];
      for (int rr = 0; rr < 4; rr++) {
        int row = m0 + mt * 16 + q * 4 + rr;
        float v = acc2[mt][nt][rr] + bc + h[(size_t)row * 256 + col];
        v *= nmask[row];
        h[(size_t)row * 256 + col] = v;
        catb[(size_t)row * 512 + col] = f2bf(v);
      }
    }
}

// ---------------- fused edge kernel: one 512-thread block per (b, i-pair).
// Ae rows 0..47 = i0, 48..95 = i1 (rows 44..47 / 92..95 zero-padded).
// 8 waves, wave tile 96x32 (acc[6][2]); B direct from bf16 W2T (L2-resident).
template<int COORD>
__global__ __launch_bounds__(512, 4)
void edge_kernel(const float* __restrict__ PQ,
                 const float* __restrict__ be1,   size_t ob1,
                 const float* __restrict__ We1raw, size_t oW1,  // for rows 512/513
                 const bf16_t* __restrict__ W2T,  size_t oW2,
                 const float* __restrict__ b2,    size_t ob2,
                 const float* __restrict__ wc3,   size_t oc3,
                 const float* __restrict__ xcur,
                 const float* __restrict__ x0g,
                 const float* __restrict__ emask,
                 const float* __restrict__ nmask,
                 bf16_t* __restrict__ aggout,
                 float* __restrict__ xnext) {
  __shared__ __align__(16) bf16_t Ae[96][264];
  __shared__ float  xjL[48][3], x0jL[48][3];
  __shared__ float2 ddL[2][48];
  __shared__ float  emLDS[2][48];
  __shared__ float  phiLDS[8][96];
  int bp = blockIdx.x;
  int b  = bp / 22;
  int ip = (bp % 22) * 2;
  int tid = threadIdx.x;
  if (tid < NNODE) {
    for (int c = 0; c < 3; c++) {
      xjL [tid][c] = xcur[(size_t)(b * NNODE + tid) * 3 + c];
      x0jL[tid][c] = x0g [(size_t)(b * NNODE + tid) * 3 + c];
    }
  }
  if (tid < 96) {
    int ii = tid / 48, j = tid % 48;
    emLDS[ii][j] = (j < NNODE) ? emask[(size_t)(b * NNODE + ip + ii) * NNODE + j] : 0.f;
  }
  __syncthreads();
  if (tid < 96) {
    int ii = tid / 48, j = tid % 48;
    int i = ip + ii;
    float2 r = make_float2(0.f, 0.f);
    if (j < NNODE) {
      float dx = xjL[i][0] - xjL[j][0];
      float dy = xjL[i][1] - xjL[j][1];
      float dz = xjL[i][2] - xjL[j][2];
      r.x = dx * dx + dy * dy + dz * dz;
      float ex = x0jL[i][0] - x0jL[j][0];
      float ey = x0jL[i][1] - x0jL[j][1];
      float ez = x0jL[i][2] - x0jL[j][2];
      r.y = ex * ex + ey * ey + ez * ez;
    }
    ddL[ii][j] = r;
  }
  __syncthreads();
  // ---- A formation: n = tid&255, half = tid>>8 (i0 / i1)
  {
    int n = tid & 255, half = tid >> 8;
    int ni = b * NNODE + ip + half;
    float pi_b = PQ[(size_t)ni * 512 + n] + be1[ob1 + n];
    float w512 = We1raw[oW1 + 512 * 256 + n];
    float w513 = We1raw[oW1 + 513 * 256 + n];
    const float* qptr = PQ + (size_t)(b * NNODE) * 512 + 256 + n;
    bf16_t* arow = &Ae[half * 48][0];
    #pragma unroll 8
    for (int j = 0; j < NNODE; j++) {
      float qv = qptr[(size_t)j * 512];
      float2 dd = ddL[half][j];
      arow[(size_t)j * 264 + n] = f2bf(silu_f(pi_b + qv + dd.x * w512 + dd.y * w513));
    }
    for (int j = NNODE; j < 48; j++) arow[(size_t)j * 264 + n] = (bf16_t)0.f;
  }
  __syncthreads();
  int w = tid >> 6, lane = tid & 63, q = lane >> 4, lr = lane & 15;
  f32x4 acc[6][2];
  for (int mt = 0; mt < 6; mt++) for (int nt = 0; nt < 2; nt++)
    for (int rr = 0; rr < 4; rr++) acc[mt][nt][rr] = 0.0f;
  const bf16_t* Bbase = W2T + oW2 + (size_t)(w * 32 + lr) * 256;
  #pragma unroll
  for (int kk = 0; kk < 256; kk += 32) {
    bf16x8 af[6], bfr[2];
    for (int mt = 0; mt < 6; mt++)
      af[mt]  = *(const bf16x8*)(&Ae[mt * 16 + lr][kk + q * 8]);
    for (int nt = 0; nt < 2; nt++)
      bfr[nt] = *(const bf16x8*)(Bbase + (size_t)nt * 16 * 256 + kk + q * 8);
    for (int mt = 0; mt < 6; mt++)
      for (int nt = 0; nt < 2; nt++)
        acc[mt][nt] = __builtin_amdgcn_mfma_f32_16x16x32_bf16(af[mt], bfr[nt], acc[mt][nt], 0, 0, 0);
  }
  // ---- epilogue
  if constexpr (!COORD) {
    for (int nt = 0; nt < 2; nt++) {
      int col = w * 32 + nt * 16 + lr;
      float bcol = b2[ob2 + col];
      float s0 = 0.f, s1 = 0.f;
      for (int mt = 0; mt < 3; mt++)
        for (int rr = 0; rr < 4; rr++) {
          int row = mt * 16 + q * 4 + rr;
          s0 += silu_f(acc[mt][nt][rr] + bcol) * emLDS[0][row];
          s1 += silu_f(acc[mt + 3][nt][rr] + bcol) * emLDS[1][row];
        }
      s0 += __shfl_xor(s0, 16, 64);  s0 += __shfl_xor(s0, 32, 64);
      s1 += __shfl_xor(s1, 16, 64);  s1 += __shfl_xor(s1, 32, 64);
      if (q == 0) {
        size_t ni0 = (size_t)(b * NNODE + ip);
        aggout[ni0 * 512 + 256 + col]       = f2bf(s0 * 0.01f);
        aggout[(ni0 + 1) * 512 + 256 + col] = f2bf(s1 * 0.01f);
      }
    }
  } else {
    for (int mt = 0; mt < 6; mt++) {
      float rs[4] = {0.f, 0.f, 0.f, 0.f};
      for (int nt = 0; nt < 2; nt++) {
        int col = w * 32 + nt * 16 + lr;
        float bcol = b2[ob2 + col];
        float wc   = wc3[oc3 + col];
        for (int rr = 0; rr < 4; rr++)
          rs[rr] += silu_f(acc[mt][nt][rr] + bcol) * wc;
      }
      for (int off = 1; off <= 8; off <<= 1)
        for (int rr = 0; rr < 4; rr++) rs[rr] += __shfl_xor(rs[rr], off, 64);
      if (lr == 0)
        for (int rr = 0; rr < 4; rr++)
          phiLDS[w][mt * 16 + q * 4 + rr] = rs[rr];
    }
    __syncthreads();
    if (tid < 128) {
      int ii = tid >> 6;
      int j = lane;
      int i = ip + ii;
      float tx = 0.f, ty = 0.f, tz = 0.f;
      if (j < NNODE) {
        float ph = 0.f;
        for (int ww = 0; ww < 8; ww++) ph += phiLDS[ww][ii * 48 + j];
        ph *= emLDS[ii][j];
        float dx = xjL[i][0] - xjL[j][0];
        float dy = xjL[i][1] - xjL[j][1];
        float dz = xjL[i][2] - xjL[j][2];
        float dd = dx * dx + dy * dy + dz * dz;
        float rinv = 1.0f / sqrtf(dd + 1e-8f);
        tx = ph * dx * rinv;
        ty = ph * dy * rinv;
        tz = ph * dz * rinv;
      }
      for (int off = 1; off <= 32; off <<= 1) {
        tx += __shfl_xor(tx, off, 64);
        ty += __shfl_xor(ty, off, 64);
        tz += __shfl_xor(tz, off, 64);
      }
      if (lane == 0) {
        size_t ni = (size_t)(b * NNODE + i);
        float nm = nmask[ni];
        xnext[ni * 3 + 0] = (xjL[i][0] + tx * 0.01f) * nm;
        xnext[ni * 3 + 1] = (xjL[i][1] + ty * 0.01f) * nm;
        xnext[ni * 3 + 2] = (xjL[i][2] + tz * 0.01f) * nm;
      }
    }
  }
}

// ---------------- output: vel (mean-subtracted) + h_final -> FLOAT32 out
__global__ __launch_bounds__(256)
void out_kernel(const float* __restrict__ h, const float* __restrict__ x,
                const float* __restrict__ x0, const float* __restrict__ nmask,
                const float* __restrict__ W_out, const float* __restrict__ b_out,
                float* __restrict__ out) {
  __shared__ float vel[NNODE][3];
  __shared__ float sums[4];
  int b = blockIdx.x, tid = threadIdx.x;
  if (tid < NNODE * 3) {
    int n = tid / 3, c = tid % 3;
    int m = b * NNODE + n;
    vel[n][c] = (x[(size_t)m * 3 + c] - x0[(size_t)m * 3 + c]) * nmask[m];
  }
  __syncthreads();
  if (tid < 4) {
    float s = 0.f;
    if (tid < 3) { for (int n = 0; n < NNODE; n++) s += vel[n][tid]; }
    else         { for (int n = 0; n < NNODE; n++) s += nmask[b * NNODE + n]; }
    sums[tid] = s;
  }
  __syncthreads();
  if (tid < NNODE * 3) {
    int n = tid / 3, c = tid % 3;
    int m = b * NNODE + n;
    float v = (vel[n][c] - sums[c] / sums[3]) * nmask[m];
    out[(size_t)m * 9 + c] = v;
  }
  for (int idx = tid; idx < NNODE * 6; idx += 256) {
    int n = idx / 6, c = idx % 6;
    int m = b * NNODE + n;
    float accv = b_out[c];
    const float* hr = h + (size_t)m * 256;
    for (int k = 0; k < 256; k++) accv += hr[k] * W_out[(size_t)k * 7 + c];
    out[(size_t)m * 9 + 3 + c] = accv * nmask[m];
  }
}

extern "C" void kernel_launch(void* const* d_in, const int* in_sizes, int n_in,
                              void* d_out, int out_size, void* d_ws, size_t ws_size,
                              hipStream_t stream) {
  const float* t       = (const float*)d_in[0];
  const float* xh      = (const float*)d_in[1];
  const float* nmask   = (const float*)d_in[2];
  const float* emask   = (const float*)d_in[3];
  const float* rep     = (const float*)d_in[4];
  const float* W_embed = (const float*)d_in[5];
  const float* b_embed = (const float*)d_in[6];
  const float* W_rep   = (const float*)d_in[7];
  const float* b_rep   = (const float*)d_in[8];
  const float* We1     = (const float*)d_in[9];
  const float* be1     = (const float*)d_in[10];
  const float* We2     = (const float*)d_in[11];
  const float* be2     = (const float*)d_in[12];
  const float* Wn1     = (const float*)d_in[13];
  const float* bn1     = (const float*)d_in[14];
  const float* Wn2     = (const float*)d_in[15];
  const float* bn2     = (const float*)d_in[16];
  const float* Wc1     = (const float*)d_in[17];
  const float* bc1     = (const float*)d_in[18];
  const float* Wc2     = (const float*)d_in[19];
  const float* bc2     = (const float*)d_in[20];
  const float* Wc3     = (const float*)d_in[21];
  const float* W_out   = (const float*)d_in[22];
  const float* b_out   = (const float*)d_in[23];

  char* p = (char*)d_ws;
  auto alloc = [&](size_t bytes) { char* r = p; p += (bytes + 255) & ~(size_t)255; return r; };
  bf16_t* We1T  = (bf16_t*)alloc((size_t)8 * 256 * 520 * 2);
  bf16_t* Wc1T  = (bf16_t*)alloc((size_t)4 * 256 * 520 * 2);
  bf16_t* We2T  = (bf16_t*)alloc((size_t)8 * 256 * 256 * 2);
  bf16_t* Wc2T  = (bf16_t*)alloc((size_t)4 * 256 * 256 * 2);
  bf16_t* Wn1T  = (bf16_t*)alloc((size_t)8 * 256 * 512 * 2);
  bf16_t* Wn2T  = (bf16_t*)alloc((size_t)8 * 256 * 256 * 2);
  float*  h_f32 = (float*) alloc((size_t)NODES * 256 * 4);
  bf16_t* cat1  = (bf16_t*)alloc((size_t)NODES * 512 * 2);
  float*  PQ    = (float*) alloc((size_t)NODES * 512 * 4);
  float*  x0buf = (float*) alloc((size_t)NODES * 3 * 4);
  float*  xA    = (float*) alloc((size_t)NODES * 3 * 4);
  float*  xB    = (float*) alloc((size_t)NODES * 3 * 4);
  float*  rproj = (float*) alloc((size_t)BSZ * 256 * 4);

  dim3 tb(32, 8);
  transpose_wb<<<dim3(8, 17, 8), tb, 0, stream>>>(We1, We1T, 514, 520);
  transpose_wb<<<dim3(8, 17, 4), tb, 0, stream>>>(Wc1, Wc1T, 514, 520);
  transpose_wb<<<dim3(8,  8, 8), tb, 0, stream>>>(We2, We2T, 256, 256);
  transpose_wb<<<dim3(8,  8, 4), tb, 0, stream>>>(Wc2, Wc2T, 256, 256);
  transpose_wb<<<dim3(8, 16, 8), tb, 0, stream>>>(Wn1, Wn1T, 512, 512);
  transpose_wb<<<dim3(8,  8, 8), tb, 0, stream>>>(Wn2, Wn2T, 256, 256);

  repproj_kernel<<<BSZ, 256, 0, stream>>>(rep, W_rep, b_rep, rproj);
  embed_kernel<<<NODES, 256, 0, stream>>>(xh, t, nmask, W_embed, b_embed, rproj,
                                          h_f32, cat1, x0buf, xA);

  float* xcur = xA;
  for (int l = 0; l < 4; l++) {
    float* xnext = (l & 1) ? xA : xB;
    for (int s = 0; s < 2; s++) {
      int k = 2 * l + s;
      size_t oWe1 = (size_t)k * 514 * 256, obe1 = (size_t)k * 256;
      size_t oWe2 = (size_t)k * 256 * 256, obe2 = (size_t)k * 256;
      size_t obn1 = (size_t)k * 256, obn2 = (size_t)k * 256;
      gemm_pq<<<dim3(4, 44, 2), 256, 0, stream>>>(
          cat1, 512, We1T + (size_t)k * 256 * 520, 520, PQ);
      edge_kernel<0><<<NODES / 2, 512, 0, stream>>>(
          PQ, be1, obe1, We1, oWe1, We2T, oWe2, be2, obe2, Wc3, 0,
          xcur, x0buf, emask, nmask, cat1, nullptr);
      node_mlp<<<NODES / 64, 256, 0, stream>>>(
          cat1, Wn1T + (size_t)k * 256 * 512, bn1, obn1,
          Wn2T + (size_t)k * 256 * 256, bn2, obn2, nmask, h_f32, cat1);
    }
    size_t oWc1 = (size_t)l * 514 * 256, obc1 = (size_t)l * 256;
    size_t oWc2 = (size_t)l * 256 * 256, obc2 = (size_t)l * 256;
    size_t oc3  = (size_t)l * 256;
    gemm_pq<<<dim3(4, 44, 2), 256, 0, stream>>>(
        cat1, 512, Wc1T + (size_t)l * 256 * 520, 520, PQ);
    edge_kernel<1><<<NODES / 2, 512, 0, stream>>>(
        PQ, bc1, obc1, Wc1, oWc1, Wc2T, oWc2, bc2, obc2, Wc3, oc3,
        xcur, x0buf, emask, nmask, nullptr, xnext);
    xcur = xnext;
  }

  out_kernel<<<BSZ, 256, 0, stream>>>(h_f32, xcur, x0buf, nmask, W_out, b_out,
                                      (float*)d_out);
}

// Round 14
// 1222.795 us; speedup vs baseline: 1.0135x; 1.0135x over previous
//
#include <hip/hip_runtime.h>

typedef __bf16 bf16_t;
typedef __bf16 bf16x8 __attribute__((ext_vector_type(8)));
typedef float  f32x4  __attribute__((ext_vector_type(4)));

#define BSZ 64
#define NNODE 44
#define NODES (BSZ*NNODE)      /* 2816 */

__device__ __forceinline__ float  bf2f(bf16_t v){ return (float)v; }
__device__ __forceinline__ bf16_t f2bf(float v){ return (bf16_t)v; }
__device__ __forceinline__ float  silu_f(float v){ return v / (1.0f + __expf(-v)); }

// ---------------- batched transpose + f32->bf16: src (G,R,256) -> dst (G,256,ldo)
__global__ void transpose_wb(const float* __restrict__ src, bf16_t* __restrict__ dst,
                             int R, int ldo) {
  __shared__ bf16_t tile[32][33];
  int g = blockIdx.z;
  src += (size_t)g * R * 256;
  dst += (size_t)g * 256 * ldo;
  int n0 = blockIdx.x * 32, r0 = blockIdx.y * 32;
  int tx = threadIdx.x, ty = threadIdx.y;   // 32 x 8
  for (int p = 0; p < 32; p += 8) {
    int r = r0 + ty + p;
    if (r < R) tile[ty + p][tx] = f2bf(src[(size_t)r * 256 + n0 + tx]);
  }
  __syncthreads();
  for (int p = 0; p < 32; p += 8) {
    int r = r0 + tx;
    if (r < R) dst[(size_t)(n0 + ty + p) * ldo + r] = tile[tx][ty + p];
  }
}

// ---------------- rproj[b][c] = rep[b]@W_rep[:,c] + b_rep[c]
__global__ __launch_bounds__(256)
void repproj_kernel(const float* __restrict__ rep, const float* __restrict__ W_rep,
                    const float* __restrict__ b_rep, float* __restrict__ out) {
  int b = blockIdx.x, c = threadIdx.x;
  float acc = b_rep[c];
  const float* r = rep + (size_t)b * 512;
  for (int k = 0; k < 512; k++) acc += r[k] * W_rep[(size_t)k * 256 + c];
  out[(size_t)b * 256 + c] = acc;
}

// ---------------- embedding; writes h_f32, cat1[:, :256], x0, xA
__global__ __launch_bounds__(256)
void embed_kernel(const float* __restrict__ xh, const float* __restrict__ t,
                  const float* __restrict__ nmask,
                  const float* __restrict__ W_embed, const float* __restrict__ b_embed,
                  const float* __restrict__ repproj,
                  float* __restrict__ h_f32, bf16_t* __restrict__ cat1,
                  float* __restrict__ x0, float* __restrict__ x) {
  int m = blockIdx.x;
  int b = m / NNODE;
  int c = threadIdx.x;
  float nm = nmask[m];
  float acc = b_embed[c] + repproj[(size_t)b * 256 + c];
  for (int kk = 0; kk < 6; kk++)
    acc += xh[(size_t)m * 9 + 3 + kk] * nm * W_embed[(size_t)kk * 256 + c];
  acc += t[b] * W_embed[6 * 256 + c];
  h_f32[(size_t)m * 256 + c] = acc;
  cat1 [(size_t)m * 512 + c] = f2bf(acc);
  if (c < 3) {
    float xv = xh[(size_t)m * 9 + c] * nm;
    x0[(size_t)m * 3 + c] = xv;
    x [(size_t)m * 3 + c] = xv;
  }
}

// ---------------- PQ GEMM, BM=64 BN=64, 4 waves of 32x32, zero LDS.
__global__ __launch_bounds__(256)
void gemm_pq(const bf16_t* __restrict__ A, int lda,
             const bf16_t* __restrict__ BT, int ldbt,
             float* __restrict__ outPQ) {
  int tid = threadIdx.x;
  int m0 = blockIdx.y * 64, n0 = blockIdx.x * 64;
  int kof = (int)blockIdx.z * 256;
  int w = tid >> 6, lane = tid & 63, q = lane >> 4, lr = lane & 15;
  int wm = w & 1, wn = w >> 1;
  f32x4 acc[2][2];
  for (int a = 0; a < 2; a++) for (int bb = 0; bb < 2; bb++)
    for (int rr = 0; rr < 4; rr++) acc[a][bb][rr] = 0.0f;
  const bf16_t* Arow0 = A  + (size_t)(m0 + wm * 32 + lr) * lda;
  const bf16_t* Brow0 = BT + (size_t)(n0 + wn * 32 + lr) * ldbt + kof;
  for (int k0 = 0; k0 < 256; k0 += 32) {
    bf16x8 af[2], bfr[2];
    for (int mt = 0; mt < 2; mt++)
      af[mt]  = *(const bf16x8*)(Arow0 + (size_t)mt * 16 * lda + k0 + q * 8);
    for (int nt = 0; nt < 2; nt++)
      bfr[nt] = *(const bf16x8*)(Brow0 + (size_t)nt * 16 * ldbt + k0 + q * 8);
    for (int mt = 0; mt < 2; mt++)
      for (int nt = 0; nt < 2; nt++)
        acc[mt][nt] = __builtin_amdgcn_mfma_f32_16x16x32_bf16(af[mt], bfr[nt], acc[mt][nt], 0, 0, 0);
  }
  for (int mt = 0; mt < 2; mt++)
    for (int nt = 0; nt < 2; nt++) {
      int col = n0 + wn * 32 + nt * 16 + lr;
      for (int rr = 0; rr < 4; rr++) {
        int row = m0 + wm * 32 + mt * 16 + q * 4 + rr;
        outPQ[(size_t)row * 512 + (size_t)blockIdx.z * 256 + col] = acc[mt][nt][rr];
      }
    }
}

// ---------------- fused node MLP: h = (h + silu([h,agg]@Wn1+bn1)@Wn2 + bn2)*nm
__global__ __launch_bounds__(256)
void node_mlp(const bf16_t* __restrict__ cat1,
              const bf16_t* __restrict__ Wn1T,   // [256 n][512 k] slice
              const float* __restrict__ bn1, size_t ob1,
              const bf16_t* __restrict__ Wn2T,   // [256 n][256 k] slice
              const float* __restrict__ bn2, size_t ob2,
              const float* __restrict__ nmask,
              float* __restrict__ h, bf16_t* __restrict__ catb) {
  __shared__ __align__(16) bf16_t t1s[64][264];
  int tid = threadIdx.x;
  int m0 = blockIdx.x * 64;
  int w = tid >> 6, lane = tid & 63, q = lane >> 4, lr = lane & 15;
  f32x4 acc[4][4];
  for (int mt = 0; mt < 4; mt++) for (int nt = 0; nt < 4; nt++)
    for (int rr = 0; rr < 4; rr++) acc[mt][nt][rr] = 0.0f;
  const bf16_t* Arow = cat1 + (size_t)(m0 + lr) * 512;
  const bf16_t* Brow = Wn1T + (size_t)(w * 64 + lr) * 512;
  for (int k0 = 0; k0 < 512; k0 += 32) {
    bf16x8 af[4], bfr[4];
    for (int mt = 0; mt < 4; mt++)
      af[mt]  = *(const bf16x8*)(Arow + (size_t)mt * 16 * 512 + k0 + q * 8);
    for (int nt = 0; nt < 4; nt++)
      bfr[nt] = *(const bf16x8*)(Brow + (size_t)nt * 16 * 512 + k0 + q * 8);
    for (int mt = 0; mt < 4; mt++)
      for (int nt = 0; nt < 4; nt++)
        acc[mt][nt] = __builtin_amdgcn_mfma_f32_16x16x32_bf16(af[mt], bfr[nt], acc[mt][nt], 0, 0, 0);
  }
  for (int mt = 0; mt < 4; mt++)
    for (int nt = 0; nt < 4; nt++) {
      int col = w * 64 + nt * 16 + lr;
      float bc = bn1[ob1 + col];
      for (int rr = 0; rr < 4; rr++) {
        int row = mt * 16 + q * 4 + rr;
        t1s[row][col] = f2bf(silu_f(acc[mt][nt][rr] + bc));
      }
    }
  __syncthreads();
  f32x4 acc2[4][4];
  for (int mt = 0; mt < 4; mt++) for (int nt = 0; nt < 4; nt++)
    for (int rr = 0; rr < 4; rr++) acc2[mt][nt][rr] = 0.0f;
  const bf16_t* Brow2 = Wn2T + (size_t)(w * 64 + lr) * 256;
  for (int k0 = 0; k0 < 256; k0 += 32) {
    bf16x8 af[4], bfr[4];
    for (int mt = 0; mt < 4; mt++)
      af[mt]  = *(const bf16x8*)(&t1s[mt * 16 + lr][k0 + q * 8]);
    for (int nt = 0; nt < 4; nt++)
      bfr[nt] = *(const bf16x8*)(Brow2 + (size_t)nt * 16 * 256 + k0 + q * 8);
    for (int mt = 0; mt < 4; mt++)
      for (int nt = 0; nt < 4; nt++)
        acc2[mt][nt] = __builtin_amdgcn_mfma_f32_16x16x32_bf16(af[mt], bfr[nt], acc2[mt][nt], 0, 0, 0);
  }
  for (int mt = 0; mt < 4; mt++)
    for (int nt = 0; nt < 4; nt++) {
      int col = w * 64 + nt * 16 + lr;
      float bc = bn2[ob2 + col];
      for (int rr = 0; rr < 4; rr++) {
        int row = m0 + mt * 16 + q * 4 + rr;
        float v = acc2[mt][nt][rr] + bc + h[(size_t)row * 256 + col];
        v *= nmask[row];
        h[(size_t)row * 256 + col] = v;
        catb[(size_t)row * 512 + col] = f2bf(v);
      }
    }
}

// ---------------- fused edge kernel: one 512-thread block per (b, i-pair).
// Q panel (44x256) cooperatively staged into LDS (bf16) with wide coalesced
// loads — kills the per-thread 44-deep serial Q-load latency chain.
template<int COORD>
__global__ __launch_bounds__(512, 4)
void edge_kernel(const float* __restrict__ PQ,
                 const float* __restrict__ be1,   size_t ob1,
                 const float* __restrict__ We1raw, size_t oW1,  // for rows 512/513
                 const bf16_t* __restrict__ W2T,  size_t oW2,
                 const float* __restrict__ b2,    size_t ob2,
                 const float* __restrict__ wc3,   size_t oc3,
                 const float* __restrict__ xcur,
                 const float* __restrict__ x0g,
                 const float* __restrict__ emask,
                 const float* __restrict__ nmask,
                 bf16_t* __restrict__ aggout,
                 float* __restrict__ xnext) {
  __shared__ __align__(16) bf16_t Ae[96][264];     // 50688 B
  __shared__ __align__(16) bf16_t Qs[NNODE][256];  // 22528 B
  __shared__ float  xjL[48][3], x0jL[48][3];
  __shared__ float2 ddL[2][48];
  __shared__ float  emLDS[2][48];
  __shared__ float  phiLDS[8][96];
  int bp = blockIdx.x;
  int b  = bp / 22;
  int ip = (bp % 22) * 2;
  int tid = threadIdx.x;
  // cooperative staging: Q panel (f32 -> bf16), coords, edge mask
  for (int e = tid * 4; e < NNODE * 256; e += 512 * 4) {
    int j = e >> 8, n = e & 255;
    f32x4 v = *(const f32x4*)(PQ + ((size_t)(b * NNODE + j) * 512 + 256 + n));
    Qs[j][n]     = f2bf(v[0]);
    Qs[j][n + 1] = f2bf(v[1]);
    Qs[j][n + 2] = f2bf(v[2]);
    Qs[j][n + 3] = f2bf(v[3]);
  }
  if (tid < NNODE) {
    for (int c = 0; c < 3; c++) {
      xjL [tid][c] = xcur[(size_t)(b * NNODE + tid) * 3 + c];
      x0jL[tid][c] = x0g [(size_t)(b * NNODE + tid) * 3 + c];
    }
  }
  if (tid >= 64 && tid < 160) {
    int tt = tid - 64;
    int ii = tt / 48, j = tt % 48;
    emLDS[ii][j] = (j < NNODE) ? emask[(size_t)(b * NNODE + ip + ii) * NNODE + j] : 0.f;
  }
  __syncthreads();
  if (tid < 96) {
    int ii = tid / 48, j = tid % 48;
    int i = ip + ii;
    float2 r = make_float2(0.f, 0.f);
    if (j < NNODE) {
      float dx = xjL[i][0] - xjL[j][0];
      float dy = xjL[i][1] - xjL[j][1];
      float dz = xjL[i][2] - xjL[j][2];
      r.x = dx * dx + dy * dy + dz * dz;
      float ex = x0jL[i][0] - x0jL[j][0];
      float ey = x0jL[i][1] - x0jL[j][1];
      float ez = x0jL[i][2] - x0jL[j][2];
      r.y = ex * ex + ey * ey + ez * ez;
    }
    ddL[ii][j] = r;
  }
  __syncthreads();
  // ---- A formation: n = tid&255, half = tid>>8 (i0 / i1); pure LDS + VALU
  {
    int n = tid & 255, half = tid >> 8;
    int ni = b * NNODE + ip + half;
    float pi_b = PQ[(size_t)ni * 512 + n] + be1[ob1 + n];
    float w512 = We1raw[oW1 + 512 * 256 + n];
    float w513 = We1raw[oW1 + 513 * 256 + n];
    bf16_t* arow = &Ae[half * 48][0];
    #pragma unroll 4
    for (int j = 0; j < NNODE; j++) {
      float qv = bf2f(Qs[j][n]);
      float2 dd = ddL[half][j];
      arow[(size_t)j * 264 + n] = f2bf(silu_f(pi_b + qv + dd.x * w512 + dd.y * w513));
    }
    for (int j = NNODE; j < 48; j++) arow[(size_t)j * 264 + n] = (bf16_t)0.f;
  }
  __syncthreads();
  int w = tid >> 6, lane = tid & 63, q = lane >> 4, lr = lane & 15;
  f32x4 acc[6][2];
  for (int mt = 0; mt < 6; mt++) for (int nt = 0; nt < 2; nt++)
    for (int rr = 0; rr < 4; rr++) acc[mt][nt][rr] = 0.0f;
  const bf16_t* Bbase = W2T + oW2 + (size_t)(w * 32 + lr) * 256;
  #pragma unroll
  for (int kk = 0; kk < 256; kk += 32) {
    bf16x8 af[6], bfr[2];
    for (int mt = 0; mt < 6; mt++)
      af[mt]  = *(const bf16x8*)(&Ae[mt * 16 + lr][kk + q * 8]);
    for (int nt = 0; nt < 2; nt++)
      bfr[nt] = *(const bf16x8*)(Bbase + (size_t)nt * 16 * 256 + kk + q * 8);
    for (int mt = 0; mt < 6; mt++)
      for (int nt = 0; nt < 2; nt++)
        acc[mt][nt] = __builtin_amdgcn_mfma_f32_16x16x32_bf16(af[mt], bfr[nt], acc[mt][nt], 0, 0, 0);
  }
  // ---- epilogue
  if constexpr (!COORD) {
    for (int nt = 0; nt < 2; nt++) {
      int col = w * 32 + nt * 16 + lr;
      float bcol = b2[ob2 + col];
      float s0 = 0.f, s1 = 0.f;
      for (int mt = 0; mt < 3; mt++)
        for (int rr = 0; rr < 4; rr++) {
          int row = mt * 16 + q * 4 + rr;
          s0 += silu_f(acc[mt][nt][rr] + bcol) * emLDS[0][row];
          s1 += silu_f(acc[mt + 3][nt][rr] + bcol) * emLDS[1][row];
        }
      s0 += __shfl_xor(s0, 16, 64);  s0 += __shfl_xor(s0, 32, 64);
      s1 += __shfl_xor(s1, 16, 64);  s1 += __shfl_xor(s1, 32, 64);
      if (q == 0) {
        size_t ni0 = (size_t)(b * NNODE + ip);
        aggout[ni0 * 512 + 256 + col]       = f2bf(s0 * 0.01f);
        aggout[(ni0 + 1) * 512 + 256 + col] = f2bf(s1 * 0.01f);
      }
    }
  } else {
    for (int mt = 0; mt < 6; mt++) {
      float rs[4] = {0.f, 0.f, 0.f, 0.f};
      for (int nt = 0; nt < 2; nt++) {
        int col = w * 32 + nt * 16 + lr;
        float bcol = b2[ob2 + col];
        float wc   = wc3[oc3 + col];
        for (int rr = 0; rr < 4; rr++)
          rs[rr] += silu_f(acc[mt][nt][rr] + bcol) * wc;
      }
      for (int off = 1; off <= 8; off <<= 1)
        for (int rr = 0; rr < 4; rr++) rs[rr] += __shfl_xor(rs[rr], off, 64);
      if (lr == 0)
        for (int rr = 0; rr < 4; rr++)
          phiLDS[w][mt * 16 + q * 4 + rr] = rs[rr];
    }
    __syncthreads();
    if (tid < 128) {
      int ii = tid >> 6;
      int j = lane;
      int i = ip + ii;
      float tx = 0.f, ty = 0.f, tz = 0.f;
      if (j < NNODE) {
        float ph = 0.f;
        for (int ww = 0; ww < 8; ww++) ph += phiLDS[ww][ii * 48 + j];
        ph *= emLDS[ii][j];
        float dx = xjL[i][0] - xjL[j][0];
        float dy = xjL[i][1] - xjL[j][1];
        float dz = xjL[i][2] - xjL[j][2];
        float dd = dx * dx + dy * dy + dz * dz;
        float rinv = 1.0f / sqrtf(dd + 1e-8f);
        tx = ph * dx * rinv;
        ty = ph * dy * rinv;
        tz = ph * dz * rinv;
      }
      for (int off = 1; off <= 32; off <<= 1) {
        tx += __shfl_xor(tx, off, 64);
        ty += __shfl_xor(ty, off, 64);
        tz += __shfl_xor(tz, off, 64);
      }
      if (lane == 0) {
        size_t ni = (size_t)(b * NNODE + i);
        float nm = nmask[ni];
        xnext[ni * 3 + 0] = (xjL[i][0] + tx * 0.01f) * nm;
        xnext[ni * 3 + 1] = (xjL[i][1] + ty * 0.01f) * nm;
        xnext[ni * 3 + 2] = (xjL[i][2] + tz * 0.01f) * nm;
      }
    }
  }
}

// ---------------- output: vel (mean-subtracted) + h_final -> FLOAT32 out
__global__ __launch_bounds__(256)
void out_kernel(const float* __restrict__ h, const float* __restrict__ x,
                const float* __restrict__ x0, const float* __restrict__ nmask,
                const float* __restrict__ W_out, const float* __restrict__ b_out,
                float* __restrict__ out) {
  __shared__ float vel[NNODE][3];
  __shared__ float sums[4];
  int b = blockIdx.x, tid = threadIdx.x;
  if (tid < NNODE * 3) {
    int n = tid / 3, c = tid % 3;
    int m = b * NNODE + n;
    vel[n][c] = (x[(size_t)m * 3 + c] - x0[(size_t)m * 3 + c]) * nmask[m];
  }
  __syncthreads();
  if (tid < 4) {
    float s = 0.f;
    if (tid < 3) { for (int n = 0; n < NNODE; n++) s += vel[n][tid]; }
    else         { for (int n = 0; n < NNODE; n++) s += nmask[b * NNODE + n]; }
    sums[tid] = s;
  }
  __syncthreads();
  if (tid < NNODE * 3) {
    int n = tid / 3, c = tid % 3;
    int m = b * NNODE + n;
    float v = (vel[n][c] - sums[c] / sums[3]) * nmask[m];
    out[(size_t)m * 9 + c] = v;
  }
  for (int idx = tid; idx < NNODE * 6; idx += 256) {
    int n = idx / 6, c = idx % 6;
    int m = b * NNODE + n;
    float accv = b_out[c];
    const float* hr = h + (size_t)m * 256;
    for (int k = 0; k < 256; k++) accv += hr[k] * W_out[(size_t)k * 7 + c];
    out[(size_t)m * 9 + 3 + c] = accv * nmask[m];
  }
}

extern "C" void kernel_launch(void* const* d_in, const int* in_sizes, int n_in,
                              void* d_out, int out_size, void* d_ws, size_t ws_size,
                              hipStream_t stream) {
  const float* t       = (const float*)d_in[0];
  const float* xh      = (const float*)d_in[1];
  const float* nmask   = (const float*)d_in[2];
  const float* emask   = (const float*)d_in[3];
  const float* rep     = (const float*)d_in[4];
  const float* W_embed = (const float*)d_in[5];
  const float* b_embed = (const float*)d_in[6];
  const float* W_rep   = (const float*)d_in[7];
  const float* b_rep   = (const float*)d_in[8];
  const float* We1     = (const float*)d_in[9];
  const float* be1     = (const float*)d_in[10];
  const float* We2     = (const float*)d_in[11];
  const float* be2     = (const float*)d_in[12];
  const float* Wn1     = (const float*)d_in[13];
  const float* bn1     = (const float*)d_in[14];
  const float* Wn2     = (const float*)d_in[15];
  const float* bn2     = (const float*)d_in[16];
  const float* Wc1     = (const float*)d_in[17];
  const float* bc1     = (const float*)d_in[18];
  const float* Wc2     = (const float*)d_in[19];
  const float* bc2     = (const float*)d_in[20];
  const float* Wc3     = (const float*)d_in[21];
  const float* W_out   = (const float*)d_in[22];
  const float* b_out   = (const float*)d_in[23];

  char* p = (char*)d_ws;
  auto alloc = [&](size_t bytes) { char* r = p; p += (bytes + 255) & ~(size_t)255; return r; };
  bf16_t* We1T  = (bf16_t*)alloc((size_t)8 * 256 * 520 * 2);
  bf16_t* Wc1T  = (bf16_t*)alloc((size_t)4 * 256 * 520 * 2);
  bf16_t* We2T  = (bf16_t*)alloc((size_t)8 * 256 * 256 * 2);
  bf16_t* Wc2T  = (bf16_t*)alloc((size_t)4 * 256 * 256 * 2);
  bf16_t* Wn1T  = (bf16_t*)alloc((size_t)8 * 256 * 512 * 2);
  bf16_t* Wn2T  = (bf16_t*)alloc((size_t)8 * 256 * 256 * 2);
  float*  h_f32 = (float*) alloc((size_t)NODES * 256 * 4);
  bf16_t* cat1  = (bf16_t*)alloc((size_t)NODES * 512 * 2);
  float*  PQ    = (float*) alloc((size_t)NODES * 512 * 4);
  float*  x0buf = (float*) alloc((size_t)NODES * 3 * 4);
  float*  xA    = (float*) alloc((size_t)NODES * 3 * 4);
  float*  xB    = (float*) alloc((size_t)NODES * 3 * 4);
  float*  rproj = (float*) alloc((size_t)BSZ * 256 * 4);

  dim3 tb(32, 8);
  transpose_wb<<<dim3(8, 17, 8), tb, 0, stream>>>(We1, We1T, 514, 520);
  transpose_wb<<<dim3(8, 17, 4), tb, 0, stream>>>(Wc1, Wc1T, 514, 520);
  transpose_wb<<<dim3(8,  8, 8), tb, 0, stream>>>(We2, We2T, 256, 256);
  transpose_wb<<<dim3(8,  8, 4), tb, 0, stream>>>(Wc2, Wc2T, 256, 256);
  transpose_wb<<<dim3(8, 16, 8), tb, 0, stream>>>(Wn1, Wn1T, 512, 512);
  transpose_wb<<<dim3(8,  8, 8), tb, 0, stream>>>(Wn2, Wn2T, 256, 256);

  repproj_kernel<<<BSZ, 256, 0, stream>>>(rep, W_rep, b_rep, rproj);
  embed_kernel<<<NODES, 256, 0, stream>>>(xh, t, nmask, W_embed, b_embed, rproj,
                                          h_f32, cat1, x0buf, xA);

  float* xcur = xA;
  for (int l = 0; l < 4; l++) {
    float* xnext = (l & 1) ? xA : xB;
    for (int s = 0; s < 2; s++) {
      int k = 2 * l + s;
      size_t oWe1 = (size_t)k * 514 * 256, obe1 = (size_t)k * 256;
      size_t oWe2 = (size_t)k * 256 * 256, obe2 = (size_t)k * 256;
      size_t obn1 = (size_t)k * 256, obn2 = (size_t)k * 256;
      gemm_pq<<<dim3(4, 44, 2), 256, 0, stream>>>(
          cat1, 512, We1T + (size_t)k * 256 * 520, 520, PQ);
      edge_kernel<0><<<NODES / 2, 512, 0, stream>>>(
          PQ, be1, obe1, We1, oWe1, We2T, oWe2, be2, obe2, Wc3, 0,
          xcur, x0buf, emask, nmask, cat1, nullptr);
      node_mlp<<<NODES / 64, 256, 0, stream>>>(
          cat1, Wn1T + (size_t)k * 256 * 512, bn1, obn1,
          Wn2T + (size_t)k * 256 * 256, bn2, obn2, nmask, h_f32, cat1);
    }
    size_t oWc1 = (size_t)l * 514 * 256, obc1 = (size_t)l * 256;
    size_t oWc2 = (size_t)l * 256 * 256, obc2 = (size_t)l * 256;
    size_t oc3  = (size_t)l * 256;
    gemm_pq<<<dim3(4, 44, 2), 256, 0, stream>>>(
        cat1, 512, Wc1T + (size_t)l * 256 * 520, 520, PQ);
    edge_kernel<1><<<NODES / 2, 512, 0, stream>>>(
        PQ, bc1, obc1, Wc1, oWc1, Wc2T, oWc2, bc2, obc2, Wc3, oc3,
        xcur, x0buf, emask, nmask, nullptr, xnext);
    xcur = xnext;
  }

  out_kernel<<<BSZ, 256, 0, stream>>>(h_f32, xcur, x0buf, nmask, W_out, b_out,
                                      (float*)d_out);
}

// Round 15
// 1016.664 us; speedup vs baseline: 1.2190x; 1.2028x over previous
//
#include <hip/hip_runtime.h>

typedef __bf16 bf16_t;
typedef __bf16 bf16x8 __attribute__((ext_vector_type(8)));
typedef float  f32x4  __attribute__((ext_vector_type(4)));

#define BSZ 64
#define NNODE 44
#define NODES (BSZ*NNODE)      /* 2816 */

__device__ __forceinline__ float  bf2f(bf16_t v){ return (float)v; }
__device__ __forceinline__ bf16_t f2bf(float v){ return (bf16_t)v; }
// fast silu: v * rcp(1 + 2^(-v*log2e)).  rcp/exp2 are ~1ulp HW ops.
__device__ __forceinline__ float  silu_f(float v){
  float e = __builtin_amdgcn_exp2f(v * -1.442695041f);
  return v * __builtin_amdgcn_rcpf(1.0f + e);
}

// ---------------- batched transpose + f32->bf16: src (G,R,256) -> dst (G,256,ldo)
__global__ void transpose_wb(const float* __restrict__ src, bf16_t* __restrict__ dst,
                             int R, int ldo) {
  __shared__ bf16_t tile[32][33];
  int g = blockIdx.z;
  src += (size_t)g * R * 256;
  dst += (size_t)g * 256 * ldo;
  int n0 = blockIdx.x * 32, r0 = blockIdx.y * 32;
  int tx = threadIdx.x, ty = threadIdx.y;   // 32 x 8
  for (int p = 0; p < 32; p += 8) {
    int r = r0 + ty + p;
    if (r < R) tile[ty + p][tx] = f2bf(src[(size_t)r * 256 + n0 + tx]);
  }
  __syncthreads();
  for (int p = 0; p < 32; p += 8) {
    int r = r0 + tx;
    if (r < R) dst[(size_t)(n0 + ty + p) * ldo + r] = tile[tx][ty + p];
  }
}

// ---------------- rproj[b][c] = rep[b]@W_rep[:,c] + b_rep[c]
__global__ __launch_bounds__(256)
void repproj_kernel(const float* __restrict__ rep, const float* __restrict__ W_rep,
                    const float* __restrict__ b_rep, float* __restrict__ out) {
  int b = blockIdx.x, c = threadIdx.x;
  float acc = b_rep[c];
  const float* r = rep + (size_t)b * 512;
  for (int k = 0; k < 512; k++) acc += r[k] * W_rep[(size_t)k * 256 + c];
  out[(size_t)b * 256 + c] = acc;
}

// ---------------- embedding; writes h_f32, cat1[:, :256], x0, xA
__global__ __launch_bounds__(256)
void embed_kernel(const float* __restrict__ xh, const float* __restrict__ t,
                  const float* __restrict__ nmask,
                  const float* __restrict__ W_embed, const float* __restrict__ b_embed,
                  const float* __restrict__ repproj,
                  float* __restrict__ h_f32, bf16_t* __restrict__ cat1,
                  float* __restrict__ x0, float* __restrict__ x) {
  int m = blockIdx.x;
  int b = m / NNODE;
  int c = threadIdx.x;
  float nm = nmask[m];
  float acc = b_embed[c] + repproj[(size_t)b * 256 + c];
  for (int kk = 0; kk < 6; kk++)
    acc += xh[(size_t)m * 9 + 3 + kk] * nm * W_embed[(size_t)kk * 256 + c];
  acc += t[b] * W_embed[6 * 256 + c];
  h_f32[(size_t)m * 256 + c] = acc;
  cat1 [(size_t)m * 512 + c] = f2bf(acc);
  if (c < 3) {
    float xv = xh[(size_t)m * 9 + c] * nm;
    x0[(size_t)m * 3 + c] = xv;
    x [(size_t)m * 3 + c] = xv;
  }
}

// ---------------- PQ GEMM, BM=64 BN=64, 4 waves of 32x32, zero LDS.
__global__ __launch_bounds__(256)
void gemm_pq(const bf16_t* __restrict__ A, int lda,
             const bf16_t* __restrict__ BT, int ldbt,
             float* __restrict__ outPQ) {
  int tid = threadIdx.x;
  int m0 = blockIdx.y * 64, n0 = blockIdx.x * 64;
  int kof = (int)blockIdx.z * 256;
  int w = tid >> 6, lane = tid & 63, q = lane >> 4, lr = lane & 15;
  int wm = w & 1, wn = w >> 1;
  f32x4 acc[2][2];
  for (int a = 0; a < 2; a++) for (int bb = 0; bb < 2; bb++)
    for (int rr = 0; rr < 4; rr++) acc[a][bb][rr] = 0.0f;
  const bf16_t* Arow0 = A  + (size_t)(m0 + wm * 32 + lr) * lda;
  const bf16_t* Brow0 = BT + (size_t)(n0 + wn * 32 + lr) * ldbt + kof;
  for (int k0 = 0; k0 < 256; k0 += 32) {
    bf16x8 af[2], bfr[2];
    for (int mt = 0; mt < 2; mt++)
      af[mt]  = *(const bf16x8*)(Arow0 + (size_t)mt * 16 * lda + k0 + q * 8);
    for (int nt = 0; nt < 2; nt++)
      bfr[nt] = *(const bf16x8*)(Brow0 + (size_t)nt * 16 * ldbt + k0 + q * 8);
    for (int mt = 0; mt < 2; mt++)
      for (int nt = 0; nt < 2; nt++)
        acc[mt][nt] = __builtin_amdgcn_mfma_f32_16x16x32_bf16(af[mt], bfr[nt], acc[mt][nt], 0, 0, 0);
  }
  for (int mt = 0; mt < 2; mt++)
    for (int nt = 0; nt < 2; nt++) {
      int col = n0 + wn * 32 + nt * 16 + lr;
      for (int rr = 0; rr < 4; rr++) {
        int row = m0 + wm * 32 + mt * 16 + q * 4 + rr;
        outPQ[(size_t)row * 512 + (size_t)blockIdx.z * 256 + col] = acc[mt][nt][rr];
      }
    }
}

// ---------------- fused node MLP: h = (h + silu([h,agg]@Wn1+bn1)@Wn2 + bn2)*nm
__global__ __launch_bounds__(256)
void node_mlp(const bf16_t* __restrict__ cat1,
              const bf16_t* __restrict__ Wn1T,   // [256 n][512 k] slice
              const float* __restrict__ bn1, size_t ob1,
              const bf16_t* __restrict__ Wn2T,   // [256 n][256 k] slice
              const float* __restrict__ bn2, size_t ob2,
              const float* __restrict__ nmask,
              float* __restrict__ h, bf16_t* __restrict__ catb) {
  __shared__ __align__(16) bf16_t t1s[64][264];
  int tid = threadIdx.x;
  int m0 = blockIdx.x * 64;
  int w = tid >> 6, lane = tid & 63, q = lane >> 4, lr = lane & 15;
  f32x4 acc[4][4];
  for (int mt = 0; mt < 4; mt++) for (int nt = 0; nt < 4; nt++)
    for (int rr = 0; rr < 4; rr++) acc[mt][nt][rr] = 0.0f;
  const bf16_t* Arow = cat1 + (size_t)(m0 + lr) * 512;
  const bf16_t* Brow = Wn1T + (size_t)(w * 64 + lr) * 512;
  for (int k0 = 0; k0 < 512; k0 += 32) {
    bf16x8 af[4], bfr[4];
    for (int mt = 0; mt < 4; mt++)
      af[mt]  = *(const bf16x8*)(Arow + (size_t)mt * 16 * 512 + k0 + q * 8);
    for (int nt = 0; nt < 4; nt++)
      bfr[nt] = *(const bf16x8*)(Brow + (size_t)nt * 16 * 512 + k0 + q * 8);
    for (int mt = 0; mt < 4; mt++)
      for (int nt = 0; nt < 4; nt++)
        acc[mt][nt] = __builtin_amdgcn_mfma_f32_16x16x32_bf16(af[mt], bfr[nt], acc[mt][nt], 0, 0, 0);
  }
  for (int mt = 0; mt < 4; mt++)
    for (int nt = 0; nt < 4; nt++) {
      int col = w * 64 + nt * 16 + lr;
      float bc = bn1[ob1 + col];
      for (int rr = 0; rr < 4; rr++) {
        int row = mt * 16 + q * 4 + rr;
        t1s[row][col] = f2bf(silu_f(acc[mt][nt][rr] + bc));
      }
    }
  __syncthreads();
  f32x4 acc2[4][4];
  for (int mt = 0; mt < 4; mt++) for (int nt = 0; nt < 4; nt++)
    for (int rr = 0; rr < 4; rr++) acc2[mt][nt][rr] = 0.0f;
  const bf16_t* Brow2 = Wn2T + (size_t)(w * 64 + lr) * 256;
  for (int k0 = 0; k0 < 256; k0 += 32) {
    bf16x8 af[4], bfr[4];
    for (int mt = 0; mt < 4; mt++)
      af[mt]  = *(const bf16x8*)(&t1s[mt * 16 + lr][k0 + q * 8]);
    for (int nt = 0; nt < 4; nt++)
      bfr[nt] = *(const bf16x8*)(Brow2 + (size_t)nt * 16 * 256 + k0 + q * 8);
    for (int mt = 0; mt < 4; mt++)
      for (int nt = 0; nt < 4; nt++)
        acc2[mt][nt] = __builtin_amdgcn_mfma_f32_16x16x32_bf16(af[mt], bfr[nt], acc2[mt][nt], 0, 0, 0);
  }
  for (int mt = 0; mt < 4; mt++)
    for (int nt = 0; nt < 4; nt++) {
      int col = w * 64 + nt * 16 + lr;
      float bc = bn2[ob2 + col];
      for (int rr = 0; rr < 4; rr++) {
        int row = m0 + mt * 16 + q * 4 + rr;
        float v = acc2[mt][nt][rr] + bc + h[(size_t)row * 256 + col];
        v *= nmask[row];
        h[(size_t)row * 256 + col] = v;
        catb[(size_t)row * 512 + col] = f2bf(v);
      }
    }
}

// ---------------- fused edge kernel: one 512-thread block per (b, i-pair).
// LDS diet (53 KB -> 3 blocks/CU): no Q staging (Q from L2), phi scratch
// aliased into Ae after the MFMA loop. Fast silu (rcp+exp2).
template<int COORD>
__global__ __launch_bounds__(512, 6)
void edge_kernel(const float* __restrict__ PQ,
                 const float* __restrict__ be1,   size_t ob1,
                 const float* __restrict__ We1raw, size_t oW1,  // for rows 512/513
                 const bf16_t* __restrict__ W2T,  size_t oW2,
                 const float* __restrict__ b2,    size_t ob2,
                 const float* __restrict__ wc3,   size_t oc3,
                 const float* __restrict__ xcur,
                 const float* __restrict__ x0g,
                 const float* __restrict__ emask,
                 const float* __restrict__ nmask,
                 bf16_t* __restrict__ aggout,
                 float* __restrict__ xnext) {
  __shared__ __align__(16) bf16_t Ae[96][264];     // 50688 B (phi scratch aliased here)
  __shared__ float  xjL[48][3], x0jL[48][3];
  __shared__ float2 ddL[2][48];
  __shared__ float  emLDS[2][48];
  int bp = blockIdx.x;
  int b  = bp / 22;
  int ip = (bp % 22) * 2;
  int tid = threadIdx.x;
  if (tid < NNODE) {
    for (int c = 0; c < 3; c++) {
      xjL [tid][c] = xcur[(size_t)(b * NNODE + tid) * 3 + c];
      x0jL[tid][c] = x0g [(size_t)(b * NNODE + tid) * 3 + c];
    }
  }
  if (tid >= 64 && tid < 160) {
    int tt = tid - 64;
    int ii = tt / 48, j = tt % 48;
    emLDS[ii][j] = (j < NNODE) ? emask[(size_t)(b * NNODE + ip + ii) * NNODE + j] : 0.f;
  }
  __syncthreads();
  if (tid < 96) {
    int ii = tid / 48, j = tid % 48;
    int i = ip + ii;
    float2 r = make_float2(0.f, 0.f);
    if (j < NNODE) {
      float dx = xjL[i][0] - xjL[j][0];
      float dy = xjL[i][1] - xjL[j][1];
      float dz = xjL[i][2] - xjL[j][2];
      r.x = dx * dx + dy * dy + dz * dz;
      float ex = x0jL[i][0] - x0jL[j][0];
      float ey = x0jL[i][1] - x0jL[j][1];
      float ez = x0jL[i][2] - x0jL[j][2];
      r.y = ex * ex + ey * ey + ez * ez;
    }
    ddL[ii][j] = r;
  }
  __syncthreads();
  // ---- A formation: n = tid&255, half = tid>>8 (i0 / i1)
  {
    int n = tid & 255, half = tid >> 8;
    int ni = b * NNODE + ip + half;
    float pi_b = PQ[(size_t)ni * 512 + n] + be1[ob1 + n];
    float w512 = We1raw[oW1 + 512 * 256 + n];
    float w513 = We1raw[oW1 + 513 * 256 + n];
    const float* qptr = PQ + (size_t)(b * NNODE) * 512 + 256 + n;
    bf16_t* arow = &Ae[half * 48][0];
    #pragma unroll 8
    for (int j = 0; j < NNODE; j++) {
      float qv = qptr[(size_t)j * 512];
      float2 dd = ddL[half][j];
      arow[(size_t)j * 264 + n] = f2bf(silu_f(pi_b + qv + dd.x * w512 + dd.y * w513));
    }
    for (int j = NNODE; j < 48; j++) arow[(size_t)j * 264 + n] = (bf16_t)0.f;
  }
  __syncthreads();
  int w = tid >> 6, lane = tid & 63, q = lane >> 4, lr = lane & 15;
  f32x4 acc[6][2];
  for (int mt = 0; mt < 6; mt++) for (int nt = 0; nt < 2; nt++)
    for (int rr = 0; rr < 4; rr++) acc[mt][nt][rr] = 0.0f;
  const bf16_t* Bbase = W2T + oW2 + (size_t)(w * 32 + lr) * 256;
  #pragma unroll
  for (int kk = 0; kk < 256; kk += 32) {
    bf16x8 af[6], bfr[2];
    for (int mt = 0; mt < 6; mt++)
      af[mt]  = *(const bf16x8*)(&Ae[mt * 16 + lr][kk + q * 8]);
    for (int nt = 0; nt < 2; nt++)
      bfr[nt] = *(const bf16x8*)(Bbase + (size_t)nt * 16 * 256 + kk + q * 8);
    for (int mt = 0; mt < 6; mt++)
      for (int nt = 0; nt < 2; nt++)
        acc[mt][nt] = __builtin_amdgcn_mfma_f32_16x16x32_bf16(af[mt], bfr[nt], acc[mt][nt], 0, 0, 0);
  }
  // ---- epilogue
  if constexpr (!COORD) {
    for (int nt = 0; nt < 2; nt++) {
      int col = w * 32 + nt * 16 + lr;
      float bcol = b2[ob2 + col];
      float s0 = 0.f, s1 = 0.f;
      for (int mt = 0; mt < 3; mt++)
        for (int rr = 0; rr < 4; rr++) {
          int row = mt * 16 + q * 4 + rr;
          s0 += silu_f(acc[mt][nt][rr] + bcol) * emLDS[0][row];
          s1 += silu_f(acc[mt + 3][nt][rr] + bcol) * emLDS[1][row];
        }
      s0 += __shfl_xor(s0, 16, 64);  s0 += __shfl_xor(s0, 32, 64);
      s1 += __shfl_xor(s1, 16, 64);  s1 += __shfl_xor(s1, 32, 64);
      if (q == 0) {
        size_t ni0 = (size_t)(b * NNODE + ip);
        aggout[ni0 * 512 + 256 + col]       = f2bf(s0 * 0.01f);
        aggout[(ni0 + 1) * 512 + 256 + col] = f2bf(s1 * 0.01f);
      }
    }
  } else {
    float* phiS = (float*)&Ae[0][0];    // 8x96 floats aliased into Ae (done with Ae)
    float rsAll[6][4];
    for (int mt = 0; mt < 6; mt++) {
      float rs[4] = {0.f, 0.f, 0.f, 0.f};
      for (int nt = 0; nt < 2; nt++) {
        int col = w * 32 + nt * 16 + lr;
        float bcol = b2[ob2 + col];
        float wc   = wc3[oc3 + col];
        for (int rr = 0; rr < 4; rr++)
          rs[rr] += silu_f(acc[mt][nt][rr] + bcol) * wc;
      }
      for (int off = 1; off <= 8; off <<= 1)
        for (int rr = 0; rr < 4; rr++) rs[rr] += __shfl_xor(rs[rr], off, 64);
      for (int rr = 0; rr < 4; rr++) rsAll[mt][rr] = rs[rr];
    }
    __syncthreads();   // all waves done reading Ae; safe to overwrite as phiS
    for (int mt = 0; mt < 6; mt++)
      if (lr == 0)
        for (int rr = 0; rr < 4; rr++)
          phiS[(size_t)w * 96 + mt * 16 + q * 4 + rr] = rsAll[mt][rr];
    __syncthreads();
    if (tid < 128) {
      int ii = tid >> 6;
      int j = lane;
      int i = ip + ii;
      float tx = 0.f, ty = 0.f, tz = 0.f;
      if (j < NNODE) {
        float ph = 0.f;
        for (int ww = 0; ww < 8; ww++) ph += phiS[(size_t)ww * 96 + ii * 48 + j];
        ph *= emLDS[ii][j];
        float dx = xjL[i][0] - xjL[j][0];
        float dy = xjL[i][1] - xjL[j][1];
        float dz = xjL[i][2] - xjL[j][2];
        float dd = dx * dx + dy * dy + dz * dz;
        float rinv = 1.0f / sqrtf(dd + 1e-8f);
        tx = ph * dx * rinv;
        ty = ph * dy * rinv;
        tz = ph * dz * rinv;
      }
      for (int off = 1; off <= 32; off <<= 1) {
        tx += __shfl_xor(tx, off, 64);
        ty += __shfl_xor(ty, off, 64);
        tz += __shfl_xor(tz, off, 64);
      }
      if (lane == 0) {
        size_t ni = (size_t)(b * NNODE + i);
        float nm = nmask[ni];
        xnext[ni * 3 + 0] = (xjL[i][0] + tx * 0.01f) * nm;
        xnext[ni * 3 + 1] = (xjL[i][1] + ty * 0.01f) * nm;
        xnext[ni * 3 + 2] = (xjL[i][2] + tz * 0.01f) * nm;
      }
    }
  }
}

// ---------------- output: vel (mean-subtracted) + h_final -> FLOAT32 out
__global__ __launch_bounds__(256)
void out_kernel(const float* __restrict__ h, const float* __restrict__ x,
                const float* __restrict__ x0, const float* __restrict__ nmask,
                const float* __restrict__ W_out, const float* __restrict__ b_out,
                float* __restrict__ out) {
  __shared__ float vel[NNODE][3];
  __shared__ float sums[4];
  int b = blockIdx.x, tid = threadIdx.x;
  if (tid < NNODE * 3) {
    int n = tid / 3, c = tid % 3;
    int m = b * NNODE + n;
    vel[n][c] = (x[(size_t)m * 3 + c] - x0[(size_t)m * 3 + c]) * nmask[m];
  }
  __syncthreads();
  if (tid < 4) {
    float s = 0.f;
    if (tid < 3) { for (int n = 0; n < NNODE; n++) s += vel[n][tid]; }
    else         { for (int n = 0; n < NNODE; n++) s += nmask[b * NNODE + n]; }
    sums[tid] = s;
  }
  __syncthreads();
  if (tid < NNODE * 3) {
    int n = tid / 3, c = tid % 3;
    int m = b * NNODE + n;
    float v = (vel[n][c] - sums[c] / sums[3]) * nmask[m];
    out[(size_t)m * 9 + c] = v;
  }
  for (int idx = tid; idx < NNODE * 6; idx += 256) {
    int n = idx / 6, c = idx % 6;
    int m = b * NNODE + n;
    float accv = b_out[c];
    const float* hr = h + (size_t)m * 256;
    for (int k = 0; k < 256; k++) accv += hr[k] * W_out[(size_t)k * 7 + c];
    out[(size_t)m * 9 + 3 + c] = accv * nmask[m];
  }
}

extern "C" void kernel_launch(void* const* d_in, const int* in_sizes, int n_in,
                              void* d_out, int out_size, void* d_ws, size_t ws_size,
                              hipStream_t stream) {
  const float* t       = (const float*)d_in[0];
  const float* xh      = (const float*)d_in[1];
  const float* nmask   = (const float*)d_in[2];
  const float* emask   = (const float*)d_in[3];
  const float* rep     = (const float*)d_in[4];
  const float* W_embed = (const float*)d_in[5];
  const float* b_embed = (const float*)d_in[6];
  const float* W_rep   = (const float*)d_in[7];
  const float* b_rep   = (const float*)d_in[8];
  const float* We1     = (const float*)d_in[9];
  const float* be1     = (const float*)d_in[10];
  const float* We2     = (const float*)d_in[11];
  const float* be2     = (const float*)d_in[12];
  const float* Wn1     = (const float*)d_in[13];
  const float* bn1     = (const float*)d_in[14];
  const float* Wn2     = (const float*)d_in[15];
  const float* bn2     = (const float*)d_in[16];
  const float* Wc1     = (const float*)d_in[17];
  const float* bc1     = (const float*)d_in[18];
  const float* Wc2     = (const float*)d_in[19];
  const float* bc2     = (const float*)d_in[20];
  const float* Wc3     = (const float*)d_in[21];
  const float* W_out   = (const float*)d_in[22];
  const float* b_out   = (const float*)d_in[23];

  char* p = (char*)d_ws;
  auto alloc = [&](size_t bytes) { char* r = p; p += (bytes + 255) & ~(size_t)255; return r; };
  bf16_t* We1T  = (bf16_t*)alloc((size_t)8 * 256 * 520 * 2);
  bf16_t* Wc1T  = (bf16_t*)alloc((size_t)4 * 256 * 520 * 2);
  bf16_t* We2T  = (bf16_t*)alloc((size_t)8 * 256 * 256 * 2);
  bf16_t* Wc2T  = (bf16_t*)alloc((size_t)4 * 256 * 256 * 2);
  bf16_t* Wn1T  = (bf16_t*)alloc((size_t)8 * 256 * 512 * 2);
  bf16_t* Wn2T  = (bf16_t*)alloc((size_t)8 * 256 * 256 * 2);
  float*  h_f32 = (float*) alloc((size_t)NODES * 256 * 4);
  bf16_t* cat1  = (bf16_t*)alloc((size_t)NODES * 512 * 2);
  float*  PQ    = (float*) alloc((size_t)NODES * 512 * 4);
  float*  x0buf = (float*) alloc((size_t)NODES * 3 * 4);
  float*  xA    = (float*) alloc((size_t)NODES * 3 * 4);
  float*  xB    = (float*) alloc((size_t)NODES * 3 * 4);
  float*  rproj = (float*) alloc((size_t)BSZ * 256 * 4);

  dim3 tb(32, 8);
  transpose_wb<<<dim3(8, 17, 8), tb, 0, stream>>>(We1, We1T, 514, 520);
  transpose_wb<<<dim3(8, 17, 4), tb, 0, stream>>>(Wc1, Wc1T, 514, 520);
  transpose_wb<<<dim3(8,  8, 8), tb, 0, stream>>>(We2, We2T, 256, 256);
  transpose_wb<<<dim3(8,  8, 4), tb, 0, stream>>>(Wc2, Wc2T, 256, 256);
  transpose_wb<<<dim3(8, 16, 8), tb, 0, stream>>>(Wn1, Wn1T, 512, 512);
  transpose_wb<<<dim3(8,  8, 8), tb, 0, stream>>>(Wn2, Wn2T, 256, 256);

  repproj_kernel<<<BSZ, 256, 0, stream>>>(rep, W_rep, b_rep, rproj);
  embed_kernel<<<NODES, 256, 0, stream>>>(xh, t, nmask, W_embed, b_embed, rproj,
                                          h_f32, cat1, x0buf, xA);

  float* xcur = xA;
  for (int l = 0; l < 4; l++) {
    float* xnext = (l & 1) ? xA : xB;
    for (int s = 0; s < 2; s++) {
      int k = 2 * l + s;
      size_t oWe1 = (size_t)k * 514 * 256, obe1 = (size_t)k * 256;
      size_t oWe2 = (size_t)k * 256 * 256, obe2 = (size_t)k * 256;
      size_t obn1 = (size_t)k * 256, obn2 = (size_t)k * 256;
      gemm_pq<<<dim3(4, 44, 2), 256, 0, stream>>>(
          cat1, 512, We1T + (size_t)k * 256 * 520, 520, PQ);
      edge_kernel<0><<<NODES / 2, 512, 0, stream>>>(
          PQ, be1, obe1, We1, oWe1, We2T, oWe2, be2, obe2, Wc3, 0,
          xcur, x0buf, emask, nmask, cat1, nullptr);
      node_mlp<<<NODES / 64, 256, 0, stream>>>(
          cat1, Wn1T + (size_t)k * 256 * 512, bn1, obn1,
          Wn2T + (size_t)k * 256 * 256, bn2, obn2, nmask, h_f32, cat1);
    }
    size_t oWc1 = (size_t)l * 514 * 256, obc1 = (size_t)l * 256;
    size_t oWc2 = (size_t)l * 256 * 256, obc2 = (size_t)l * 256;
    size_t oc3  = (size_t)l * 256;
    gemm_pq<<<dim3(4, 44, 2), 256, 0, stream>>>(
        cat1, 512, Wc1T + (size_t)l * 256 * 520, 520, PQ);
    edge_kernel<1><<<NODES / 2, 512, 0, stream>>>(
        PQ, bc1, obc1, Wc1, oWc1, Wc2T, oWc2, bc2, obc2, Wc3, oc3,
        xcur, x0buf, emask, nmask, nullptr, xnext);
    xcur = xnext;
  }

  out_kernel<<<BSZ, 256, 0, stream>>>(h_f32, xcur, x0buf, nmask, W_out, b_out,
                                      (float*)d_out);
}